// Round 2
// baseline (798.096 us; speedup 1.0000x reference)
//
#include <hip/hip_runtime.h>

// LSTM forward scan: T=1024, B=16, NH=12, HD=64, NG=4 (i,f,z,o).
// One block per (b,n) recurrence chain: 192 blocks x 256 threads.
// thread tid = o*4+g (g innermost -> coalesced Wx reads).
// R[n,g,o,0:64] held in 64 VGPRs per thread — PINNED via empty asm so the
// compiler cannot sink/reload them (round-1 showed VGPR_Count=52 -> R was
// being re-fetched every step; that was the 4x slowdown).
// h/c in 1KB double-buffered LDS; gate exchange via 3 independent shfl_xor;
// ONE barrier per step. Depth-4 Wx prefetch ring.

#define T_SEQ 1024
#define B_    16
#define NH_   12
#define HD_   64
#define NG_   4
#define BN_   (B_*NH_)                    // 192 chains
#define WX_T_STRIDE (BN_*HD_*NG_)         // 49152 floats per timestep
#define OUT_T_STRIDE (BN_*HD_)            // 12288 floats per timestep
#define OUT_S_STRIDE ((T_SEQ+1)*OUT_T_STRIDE)

__global__ __launch_bounds__(256, 1)
void flashrnn_lstm_fwd(const float* __restrict__ Wx,
                       const float* __restrict__ s0,
                       const float* __restrict__ R,
                       const float* __restrict__ bias,
                       float* __restrict__ out)
{
    const int bid = blockIdx.x;           // 0..191
    const int n   = bid % NH_;
    const int b   = bid / NH_;
    const int bn  = b*NH_ + n;
    const int tid = threadIdx.x;          // 0..255
    const int o   = tid >> 2;             // output index 0..63
    const int g   = tid & 3;              // gate 0..3 (i,f,z,o)

    __shared__ float hc[2][128];          // [buf][0:64)=h, [64:128)=c

    // --- R row into registers: R[n][g][o][0:64] (contiguous, 16 x float4) ---
    float4 Rr[16];
    const float* Rp = R + ((size_t)((n*NG_ + g)*HD_ + o)) * HD_;
    #pragma unroll
    for (int k = 0; k < 16; ++k) Rr[k] = ((const float4*)Rp)[k];
    // Pin all 64 values into VGPRs: opaque to the optimizer, cannot be
    // rematerialized or spilled-by-choice back to a global reload.
    #pragma unroll
    for (int k = 0; k < 16; ++k)
        asm volatile("" : "+v"(Rr[k].x), "+v"(Rr[k].y), "+v"(Rr[k].z), "+v"(Rr[k].w));

    const float bval = bias[(n*NG_ + g)*HD_ + o];

    // c state lives (validly) only in g==0 lanes; loaded by all for simplicity
    float c = s0[BN_*HD_ + bn*HD_ + o];

    // --- init h/c in LDS buf 0 + write t=0 output slice ---
    float* stp = out;                     // dummy for tid>=128
    if (tid < 128) {
        const int d = tid & 63;
        const size_t sofs = (tid < 64) ? (size_t)0 : (size_t)OUT_S_STRIDE;
        const float v = (tid < 64) ? s0[bn*HD_ + d] : s0[BN_*HD_ + bn*HD_ + d];
        hc[0][tid] = v;
        out[sofs + (size_t)bn*HD_ + d] = v;                          // t = 0
        stp = out + sofs + (size_t)OUT_T_STRIDE + (size_t)bn*HD_ + d; // t = 1
    }

    // unified activation: a = m * rcp(1 + exp2(s*x)) + k
    // g in {0,1,3}: sigmoid (s=-log2e, m=1, k=0); g==2: tanh (s=-2log2e, m=2, k=-1)
    const float s_coef = (g == 2) ? -2.88539008f : -1.44269504f;
    const float m_coef = (g == 2) ? 2.0f : 1.0f;
    const float a_coef = (g == 2) ? -1.0f : 0.0f;

    // --- Wx prefetch ring (depth 4) ---
    const float* wxp = Wx + (size_t)bn*(HD_*NG_) + tid;
    float wxq[4];
    #pragma unroll
    for (int k = 0; k < 4; ++k) wxq[k] = wxp[(size_t)k * WX_T_STRIDE];

    __syncthreads();

#define STEP(TT, SLOT, CUR)                                                    \
    {                                                                          \
        const int t = tb + (TT);                                               \
        const float wxv = wxq[SLOT];                                           \
        { int tl = t + 4; if (tl > T_SEQ-1) tl = T_SEQ-1;                      \
          wxq[SLOT] = wxp[(size_t)tl * WX_T_STRIDE]; }                         \
        float4 acc = make_float4(0.f, 0.f, 0.f, 0.f);                          \
        const float4* hv = (const float4*)&hc[CUR][0];                         \
        _Pragma("unroll")                                                      \
        for (int k = 0; k < 16; ++k) {                                         \
            const float4 h4 = hv[k];                                           \
            acc.x = fmaf(Rr[k].x, h4.x, acc.x);                                \
            acc.y = fmaf(Rr[k].y, h4.y, acc.y);                                \
            acc.z = fmaf(Rr[k].z, h4.z, acc.z);                                \
            acc.w = fmaf(Rr[k].w, h4.w, acc.w);                                \
        }                                                                      \
        const float gp = ((acc.x+acc.y)+(acc.z+acc.w)) + wxv + bval;           \
        const float ev = __builtin_amdgcn_exp2f(s_coef * gp);                  \
        const float rv = __builtin_amdgcn_rcpf(1.0f + ev);                     \
        const float a  = fmaf(m_coef, rv, a_coef);                             \
        const float v1 = __shfl_xor(a, 1);   /* gate g^1 */                    \
        const float v2 = __shfl_xor(a, 2);   /* gate g^2 */                    \
        const float v3 = __shfl_xor(a, 3);   /* gate g^3 */                    \
        /* valid only for g==0: i=a, f=v1, z=v2, o=v3 */                       \
        c = fmaf(v1, c, a * v2);                                               \
        const float e2 = __builtin_amdgcn_exp2f(-2.88539008f * c);             \
        const float th = fmaf(2.0f, __builtin_amdgcn_rcpf(1.0f + e2), -1.0f);  \
        const float hval = v3 * th;                                            \
        if (g == 0) { hc[(CUR)^1][o] = hval; hc[(CUR)^1][64+o] = c; }          \
        __syncthreads();                                                       \
        if (tid < 128) { *stp = hc[(CUR)^1][tid]; stp += OUT_T_STRIDE; }       \
    }

    for (int tb = 0; tb < T_SEQ; tb += 4) {
        STEP(0, 0, 0)
        STEP(1, 1, 1)
        STEP(2, 2, 0)
        STEP(3, 3, 1)
    }
#undef STEP
}

extern "C" void kernel_launch(void* const* d_in, const int* in_sizes, int n_in,
                              void* d_out, int out_size, void* d_ws, size_t ws_size,
                              hipStream_t stream) {
    const float* Wx = (const float*)d_in[0];
    const float* s0 = (const float*)d_in[1];
    const float* R  = (const float*)d_in[2];
    const float* bb = (const float*)d_in[3];
    float* out = (float*)d_out;
    flashrnn_lstm_fwd<<<dim3(BN_), dim3(256), 0, stream>>>(Wx, s0, R, bb, out);
}

// Round 3
// 673.847 us; speedup vs baseline: 1.1844x; 1.1844x over previous
//
#include <hip/hip_runtime.h>

// LSTM forward scan: T=1024, B=16, NH=12, HD=64, NG=4 (i,f,z,o).
// One block per (b,n) chain: 192 blocks x 256 threads; tid = o*4+g.
//
// Round-2 lessons:
//  * float4 Rr[16] + asm pin on elements => alloca address taken => SROA
//    defeated => R lived in SCRATCH (VGPR_Count=48). Fix: 16 NAMED float4
//    scalars — no array, no alloca possible.
//  * __syncthreads() emits s_waitcnt vmcnt(0) before s_barrier, draining the
//    Wx prefetch ring every step (~900cyc HBM latency on the critical path).
//    Fix: raw `s_waitcnt lgkmcnt(0); s_barrier` — LDS handoff stays ordered,
//    global prefetch loads stay in flight across the barrier.

#define T_SEQ 1024
#define B_    16
#define NH_   12
#define HD_   64
#define NG_   4
#define BN_   (B_*NH_)                    // 192 chains
#define WX_T_STRIDE (BN_*HD_*NG_)         // 49152 floats per timestep
#define OUT_T_STRIDE (BN_*HD_)            // 12288 floats per timestep
#define OUT_S_STRIDE ((T_SEQ+1)*OUT_T_STRIDE)

// raw workgroup barrier: orders LDS (lgkmcnt) but does NOT drain vmcnt —
// keeps the global prefetch ring in flight across steps.
#define LDS_BARRIER() asm volatile("s_waitcnt lgkmcnt(0)\n\ts_barrier" ::: "memory")

__global__ __launch_bounds__(256, 1) __attribute__((amdgpu_waves_per_eu(1)))
void flashrnn_lstm_fwd(const float* __restrict__ Wx,
                       const float* __restrict__ s0,
                       const float* __restrict__ R,
                       const float* __restrict__ bias,
                       float* __restrict__ out)
{
    const int bid = blockIdx.x;           // 0..191
    const int n   = bid % NH_;
    const int b   = bid / NH_;
    const int bn  = b*NH_ + n;
    const int tid = threadIdx.x;          // 0..255
    const int o   = tid >> 2;             // output index 0..63
    const int g   = tid & 3;              // gate 0..3 (i,f,z,o)

    __shared__ float hc[2][128];          // [buf][0:64)=h, [64:128)=c

    // --- R row R[n][g][o][0:64] into 16 NAMED float4 registers ---
    const float4* Rp = (const float4*)(R + ((size_t)((n*NG_ + g)*HD_ + o)) * HD_);
    float4 r0 = Rp[0],  r1 = Rp[1],  r2 = Rp[2],  r3 = Rp[3];
    float4 r4 = Rp[4],  r5 = Rp[5],  r6 = Rp[6],  r7 = Rp[7];
    float4 r8 = Rp[8],  r9 = Rp[9],  r10 = Rp[10], r11 = Rp[11];
    float4 r12 = Rp[12], r13 = Rp[13], r14 = Rp[14], r15 = Rp[15];

    const float bval = bias[(n*NG_ + g)*HD_ + o];

    // c state lives (validly) only in g==0 lanes
    float c = s0[BN_*HD_ + bn*HD_ + o];

    // --- init h/c in LDS buf 0 + write t=0 output slice ---
    float* stp = out;                     // dummy for tid>=128
    if (tid < 128) {
        const int d = tid & 63;
        const size_t sofs = (tid < 64) ? (size_t)0 : (size_t)OUT_S_STRIDE;
        const float v = (tid < 64) ? s0[bn*HD_ + d] : s0[BN_*HD_ + bn*HD_ + d];
        hc[0][tid] = v;
        out[sofs + (size_t)bn*HD_ + d] = v;                           // t = 0
        stp = out + sofs + (size_t)OUT_T_STRIDE + (size_t)bn*HD_ + d; // t = 1
    }

    // unified activation: a = m * rcp(1 + exp2(s*x)) + k
    // g in {0,1,3}: sigmoid; g==2: tanh
    const float s_coef = (g == 2) ? -2.88539008f : -1.44269504f;
    const float m_coef = (g == 2) ? 2.0f : 1.0f;
    const float a_coef = (g == 2) ? -1.0f : 0.0f;

    // --- Wx prefetch ring (depth 4), named scalars ---
    const float* wxp = Wx + (size_t)bn*(HD_*NG_) + tid;
    float wx0 = wxp[0];
    float wx1 = wxp[(size_t)1 * WX_T_STRIDE];
    float wx2 = wxp[(size_t)2 * WX_T_STRIDE];
    float wx3 = wxp[(size_t)3 * WX_T_STRIDE];

    __syncthreads();   // one full barrier before the loop (drains init loads)

#define STEP(TT, SLOT, CUR)                                                    \
    {                                                                          \
        const float wxv = wx##SLOT;                                            \
        { int tl = tb + (TT) + 4; if (tl > T_SEQ-1) tl = T_SEQ-1;              \
          wx##SLOT = wxp[(size_t)tl * WX_T_STRIDE]; }                          \
        float4 acc = make_float4(0.f, 0.f, 0.f, 0.f);                          \
        const float4* hv = (const float4*)&hc[CUR][0];                         \
        const float4 h0 = hv[0],  h1 = hv[1],  h2 = hv[2],  h3 = hv[3];        \
        const float4 h4 = hv[4],  h5 = hv[5],  h6 = hv[6],  h7 = hv[7];        \
        const float4 h8 = hv[8],  h9 = hv[9],  h10 = hv[10], h11 = hv[11];     \
        const float4 h12 = hv[12], h13 = hv[13], h14 = hv[14], h15 = hv[15];   \
        DOT(r0,h0)  DOT(r1,h1)  DOT(r2,h2)  DOT(r3,h3)                         \
        DOT(r4,h4)  DOT(r5,h5)  DOT(r6,h6)  DOT(r7,h7)                         \
        DOT(r8,h8)  DOT(r9,h9)  DOT(r10,h10) DOT(r11,h11)                      \
        DOT(r12,h12) DOT(r13,h13) DOT(r14,h14) DOT(r15,h15)                    \
        const float gp = ((acc.x+acc.y)+(acc.z+acc.w)) + wxv + bval;           \
        const float ev = __builtin_amdgcn_exp2f(s_coef * gp);                  \
        const float rv = __builtin_amdgcn_rcpf(1.0f + ev);                     \
        const float a  = fmaf(m_coef, rv, a_coef);                             \
        const float v1 = __shfl_xor(a, 1);   /* gate g^1 */                    \
        const float v2 = __shfl_xor(a, 2);   /* gate g^2 */                    \
        const float v3 = __shfl_xor(a, 3);   /* gate g^3 */                    \
        /* valid only for g==0: i=a, f=v1, z=v2, o=v3 */                       \
        c = fmaf(v1, c, a * v2);                                               \
        const float e2 = __builtin_amdgcn_exp2f(-2.88539008f * c);             \
        const float th = fmaf(2.0f, __builtin_amdgcn_rcpf(1.0f + e2), -1.0f);  \
        const float hval = v3 * th;                                            \
        if (g == 0) { hc[(CUR)^1][o] = hval; hc[(CUR)^1][64+o] = c; }          \
        LDS_BARRIER();                                                         \
        if (tid < 128) { *stp = hc[(CUR)^1][tid]; stp += OUT_T_STRIDE; }       \
    }

#define DOT(R4, H4)                                                            \
        acc.x = fmaf((R4).x, (H4).x, acc.x);                                   \
        acc.y = fmaf((R4).y, (H4).y, acc.y);                                   \
        acc.z = fmaf((R4).z, (H4).z, acc.z);                                   \
        acc.w = fmaf((R4).w, (H4).w, acc.w);

    for (int tb = 0; tb < T_SEQ; tb += 4) {
        STEP(0, 0, 0)
        STEP(1, 1, 1)
        STEP(2, 2, 0)
        STEP(3, 3, 1)
    }
#undef STEP
#undef DOT
}

extern "C" void kernel_launch(void* const* d_in, const int* in_sizes, int n_in,
                              void* d_out, int out_size, void* d_ws, size_t ws_size,
                              hipStream_t stream) {
    const float* Wx = (const float*)d_in[0];
    const float* s0 = (const float*)d_in[1];
    const float* R  = (const float*)d_in[2];
    const float* bb = (const float*)d_in[3];
    float* out = (float*)d_out;
    flashrnn_lstm_fwd<<<dim3(BN_), dim3(256), 0, stream>>>(Wx, s0, R, bb, out);
}